// Round 8
// baseline (2762.540 us; speedup 1.0000x reference)
//
#include <hip/hip_runtime.h>

// Fsmm_rnn: 2-layer tanh RNN (B=64,T=2048,D=4,H=256) + closed-form last-step
// grad + fractional-memory Up at t=T-1 + (64,64) broadcast assemblies.
//
// v6 = v5 + direct VGPR-budget pin.
// Post-mortem law (v1..v5): allocator budgets VGPRs from flat-workgroup-size
// alone (targets 2 blocks/CU: 4w->256, 8w->128, 16w->64 regs) and IGNORES
// LDS-forced occupancy (v5: LDS=106KB forced 1 WG/CU yet budget stayed 64 ->
// 26MB scratch, VGPR_Count=64). v3's amdgpu_waves_per_eu(2,2) was masked by
// __launch_bounds__ arg2 emitting its own waves-per-eu min. Fix: launch_bounds
// WITHOUT arg2 + amdgpu_waves_per_eu(4,4) + amdgpu_num_vgpr(128). 16-wave WG
// at 1 WG/CU (LDS pad) = exactly 4 waves/EU -> budget 512/4 = 128. Demand
// ~126 (96 weight h2 + ~30 working) fits -> no spill.

#define TT 2048
#define HH 256
#define WIN 64

typedef _Float16 h2 __attribute__((ext_vector_type(2)));
typedef uint uvec32 __attribute__((ext_vector_type(32)));

__device__ __forceinline__ float fdot2p(h2 a, h2 b, float c) {
  return __builtin_amdgcn_fdot2(a, b, c, false);
}
__device__ __forceinline__ h2 bc2(unsigned u) {
  return __builtin_bit_cast(h2, u);
}

__device__ __forceinline__ float tanh_fast(float x) {
  float xc = fminf(fmaxf(x, -15.f), 15.f);
  float e = __expf(2.f * xc);
  return (e - 1.f) * __builtin_amdgcn_rcpf(e + 1.f);
}

// 1024-thread (16-wave) block sum, broadcast to all threads.
__device__ __forceinline__ float block_sum16(float v, float* red, int tid) {
#pragma unroll
  for (int off = 32; off >= 1; off >>= 1) v += __shfl_down(v, off, 64);
  __syncthreads();  // protect red reuse across calls
  if ((tid & 63) == 0) red[tid >> 6] = v;
  __syncthreads();
  float s = 0.f;
#pragma unroll
  for (int w = 0; w < 16; ++w) s += red[w];
  return s;
}

// Load+convert a 64-col quarter row (f32 global) into packed-h2 uvec32 (32 VGPRs).
__device__ __forceinline__ uvec32 ld_quarter(const float* __restrict__ base) {
  uvec32 w;
  const float4* g = (const float4*)base;
#pragma unroll
  for (int i = 0; i < 16; ++i) {
    float4 a = g[i];
    h2 t0; t0.x = (_Float16)a.x; t0.y = (_Float16)a.y;
    h2 t1; t1.x = (_Float16)a.z; t1.y = (_Float16)a.w;
    w[2 * i] = __builtin_bit_cast(uint, t0);
    w[2 * i + 1] = __builtin_bit_cast(uint, t1);
  }
  return w;
}

// 64-col quarter dot vs broadcast h vector (8 uint4 uniform LDS reads).
#define DOTQ(WV, HP, A0, A1, A2, A3)                                       \
  {                                                                        \
    _Pragma("unroll") for (int _i = 0; _i < 8; ++_i) {                     \
      uint4 _u = (HP)[_i];                                                 \
      A0 = fdot2p(bc2(WV[4 * _i + 0]), bc2(_u.x), A0);                     \
      A1 = fdot2p(bc2(WV[4 * _i + 1]), bc2(_u.y), A1);                     \
      A2 = fdot2p(bc2(WV[4 * _i + 2]), bc2(_u.z), A2);                     \
      A3 = fdot2p(bc2(WV[4 * _i + 3]), bc2(_u.w), A3);                     \
    }                                                                      \
  }

__global__ void __launch_bounds__(1024)
__attribute__((amdgpu_waves_per_eu(4, 4), amdgpu_num_vgpr(128)))
rnn_chain_kernel(
    const float* __restrict__ x, const float* __restrict__ Wih0,
    const float* __restrict__ Whh0, const float* __restrict__ bih0,
    const float* __restrict__ bhh0, const float* __restrict__ Wih1,
    const float* __restrict__ Whh1, const float* __restrict__ bih1,
    const float* __restrict__ bhh1, const float* __restrict__ fcW,
    const float* __restrict__ fcb, const float* __restrict__ f1W,
    const float* __restrict__ f1b, const float* __restrict__ f2W,
    const float* __restrict__ f2b, const float* __restrict__ C1,
    const float* __restrict__ R1, const float* __restrict__ binom,
    float* __restrict__ out_soc,  // d_out[0..64)
    float* __restrict__ ws)       // [0..64) d_soc, [64..128) f_soc, [128..192) Up_last
{
  const int b = blockIdx.x;
  const int tid = threadIdx.x;
  const int j = tid & 255;    // row
  const int q = tid >> 8;     // quarter: cols [64q, 64q+64)

  __shared__ __align__(16) float xs[TT * 4];   // 32 KB: whole x[b]
  __shared__ __align__(16) _Float16 h0L[HH];   // current h0 (f16)
  __shared__ __align__(16) _Float16 h1L[HH];   // current h1 (f16)
  __shared__ float pZ0[4 * HH];  // a-partials, plane per quarter
  __shared__ float pZ1[4 * HH];  // (e+c)-partials
  __shared__ float red[16];
  __shared__ float uL[HH];
  // Occupancy forcing pad: lifts static LDS to ~102KB so only 1 workgroup
  // fits per CU -> 16 waves/CU -> exactly 4 waves/EU (matches the (4,4)
  // attribute; registers freed by the 128-budget cost zero occupancy).
  __shared__ float occ_pad[16384];  // 64 KB

  // ---- preload x[b] into LDS (coalesced float4) ----
  const float4* xg = (const float4*)(x + (size_t)b * TT * 4);
  float4* xl = (float4*)xs;
  for (int i = tid; i < TT; i += 1024) xl[i] = xg[i];

  // ---- weight quarter-rows as SSA vectors (96 VGPRs total) ----
  const size_t roff = (size_t)j * HH + q * 64;
  const uvec32 w0  = ld_quarter(Whh0 + roff);
  const uvec32 w1i = ld_quarter(Wih1 + roff);
  const uvec32 w1h = ld_quarter(Whh1 + roff);

  const float4 wx = ((const float4*)Wih0)[j];  // row j of Wih0 (D=4), used by q==0
  const float bias0 = bih0[j] + bhh0[j];
  const float bias1 = bih1[j] + bhh1[j];

  __syncthreads();  // xs ready

  // keep occ_pad alive (one dead-cheap volatile store; tid==1023 exists)
  if (tid == 1023) ((volatile float*)occ_pad)[0] = xs[0];

  // ---- prologue: h0[0] = tanh(Wih0 x0 + b0), h1[-1] = 0 ----
  if (q == 0) {
    float4 x0v = xl[0];
    float z = wx.x * x0v.x + wx.y * x0v.y + wx.z * x0v.z + wx.w * x0v.w + bias0;
    h0L[j] = (_Float16)tanh_fast(z);
  } else if (q == 1) {
    h1L[j] = (_Float16)0.f;
  }
  __syncthreads();

  const uint4* h0p = (const uint4*)h0L + q * 8;  // quarter of h0 (64 halves)
  const uint4* h1p = (const uint4*)h1L + q * 8;

  float h0T = 0.f;  // q==0: f32 h0[T-1]
  float h1T = 0.f;  // q==1: f32 h1[T-1]

  // ---- fused scan: iteration t computes h1[t] and h0[t+1]; t = 0..T-2 ----
  for (int t = 0; t < TT - 1; ++t) {
    // c = Whh1 quarter . h1[t-1]
    float c0 = 0, c1 = 0, c2 = 0, c3 = 0;
    DOTQ(w1h, h1p, c0, c1, c2, c3);
    float ec = (c0 + c1) + (c2 + c3);
    // shared pass over h0[t]: e (Wih1) and a (Whh0)
    float e0 = 0, e1 = 0, e2 = 0, e3 = 0;
    float a0 = 0, a1 = 0, a2 = 0, a3 = 0;
#pragma unroll
    for (int i = 0; i < 8; ++i) {
      uint4 u = h0p[i];
      e0 = fdot2p(bc2(w1i[4 * i + 0]), bc2(u.x), e0);
      a0 = fdot2p(bc2(w0[4 * i + 0]), bc2(u.x), a0);
      e1 = fdot2p(bc2(w1i[4 * i + 1]), bc2(u.y), e1);
      a1 = fdot2p(bc2(w0[4 * i + 1]), bc2(u.y), a1);
      e2 = fdot2p(bc2(w1i[4 * i + 2]), bc2(u.z), e2);
      a2 = fdot2p(bc2(w0[4 * i + 2]), bc2(u.z), a2);
      e3 = fdot2p(bc2(w1i[4 * i + 3]), bc2(u.w), e3);
      a3 = fdot2p(bc2(w0[4 * i + 3]), bc2(u.w), a3);
    }
    ec += (e0 + e1) + (e2 + e3);
    float a = (a0 + a1) + (a2 + a3);
    pZ0[q * HH + j] = a;   // conflict-free (consecutive lanes, consecutive addrs)
    pZ1[q * HH + j] = ec;
    __syncthreads();
    if (q == 0) {
      float4 xt = xl[t + 1];
      float z0 = pZ0[j] + pZ0[HH + j] + pZ0[2 * HH + j] + pZ0[3 * HH + j] +
                 wx.x * xt.x + wx.y * xt.y + wx.z * xt.z + wx.w * xt.w + bias0;
      h0T = tanh_fast(z0);
      h0L[j] = (_Float16)h0T;
    } else if (q == 1) {
      float z1 = pZ1[j] + pZ1[HH + j] + pZ1[2 * HH + j] + pZ1[3 * HH + j] +
                 bias1;
      h1T = tanh_fast(z1);
      h1L[j] = (_Float16)h1T;
    }
    __syncthreads();
  }

  // ---- final step: h1[T-1] only ----
  {
    float c0 = 0, c1 = 0, c2 = 0, c3 = 0;
    DOTQ(w1h, h1p, c0, c1, c2, c3);
    float e0 = 0, e1 = 0, e2 = 0, e3 = 0;
    DOTQ(w1i, h0p, e0, e1, e2, e3);
    float ec = ((c0 + c1) + (c2 + c3)) + ((e0 + e1) + (e2 + e3));
    pZ1[q * HH + j] = ec;
    __syncthreads();
    if (q == 1) {
      float z1 = pZ1[j] + pZ1[HH + j] + pZ1[2 * HH + j] + pZ1[3 * HH + j] +
                 bias1;
      h1T = tanh_fast(z1);
      h1L[j] = (_Float16)h1T;
    }
    __syncthreads();
  }
  // Now: q==0 threads hold f32 h0T = h0[T-1]; q==1 threads hold f32 h1T.

  // ---- epilogue ----
  const float fw = fcW[j];

  float socb =
      block_sum16(q == 1 ? fw * h1T : 0.f, red, tid) + fcb[0];
  if (tid == 0) out_soc[b] = socb;

  float fsv = (q == 1) ? f2W[j] * (socb * f1W[j] + f1b[j]) : 0.f;
  float fsb = block_sum16(fsv, red, tid) + f2b[0];
  if (tid == 0) ws[64 + b] = fsb;

  // d_soc: u[k] = fcW[k](1-h1T[k]^2); g[h] = sum_k u[k] Wih1[k,h];
  //        dsoc = sum_h g[h] (1-h0T[h]^2) Wih0[h,3]
  if (q == 1) uL[j] = fw * (1.f - h1T * h1T);
  __syncthreads();
  {
    float g = 0.f;
    const int k0 = q * 64;
#pragma unroll 8
    for (int k = 0; k < 64; ++k)
      g += uL[k0 + k] * Wih1[(size_t)(k0 + k) * HH + j];  // coalesced over j
    pZ0[q * HH + j] = g;
  }
  __syncthreads();
  float dsv = 0.f;
  if (q == 0) {
    float g = pZ0[j] + pZ0[HH + j] + pZ0[2 * HH + j] + pZ0[3 * HH + j];
    dsv = g * (1.f - h0T * h0T) * wx.w;
  }
  float dsoc = block_sum16(dsv, red, tid);
  if (tid == 0) ws[b] = dsoc;

  // Up[:, -1]: Ts = sqrt((time[T-1]-time[T-64])/63); hist = sum binom[k+1]*v[T-64+k]
  float histv = 0.f;
  if (tid < WIN) histv = binom[tid + 1] * xs[(TT - WIN + tid) * 4 + 0];
  float hist = block_sum16(histv, red, tid);
  if (tid == 0) {
    float tl = xs[(TT - 1) * 4 + 3], t0v = xs[(TT - WIN) * 4 + 3];
    float tdiff = (tl - t0v) * (1.0f / (float)(WIN - 1));
    float Ts = sqrtf(tdiff);
    float vlast = xs[(TT - 1) * 4 + 0], Ilast = xs[(TT - 1) * 4 + 1];
    float r1 = R1[0], c1v = C1[0];
    float up = -Ts / (r1 * c1v) * vlast + Ts / c1v * Ilast - hist;
    ws[128 + b] = up;
  }
}

__global__ void assemble_kernel(const float* __restrict__ x,
                                const float* __restrict__ Q,
                                const float* __restrict__ delta,
                                const float* __restrict__ R0,
                                const float* __restrict__ ws,
                                float* __restrict__ out) {
  const int i = blockIdx.x;    // row (batch)
  const int jj = threadIdx.x;  // col 0..63
  const float dq = delta[0] / Q[0];
  const size_t base = ((size_t)i * TT + (TT - 1)) * 4;
  const float xv0 = x[base + 0];
  const float xv1 = x[base + 1];
  const float fs = ws[64 + i];
  // loss1[i,j] = delta/Q * x[i,-1,1] + d_soc[j]
  out[64 + i * 64 + jj] = dq * xv1 + ws[jj];
  // loss2[i,j] = f_soc[i] - x[i,-1,0] - R0*x[i,-1,1] - Up_last[j]
  out[64 + 4096 + i * 64 + jj] = fs - xv0 - R0[0] * xv1 - ws[128 + jj];
}

extern "C" void kernel_launch(void* const* d_in, const int* in_sizes, int n_in,
                              void* d_out, int out_size, void* d_ws,
                              size_t ws_size, hipStream_t stream) {
  const float* x    = (const float*)d_in[0];
  const float* Wih0 = (const float*)d_in[1];
  const float* Whh0 = (const float*)d_in[2];
  const float* bih0 = (const float*)d_in[3];
  const float* bhh0 = (const float*)d_in[4];
  const float* Wih1 = (const float*)d_in[5];
  const float* Whh1 = (const float*)d_in[6];
  const float* bih1 = (const float*)d_in[7];
  const float* bhh1 = (const float*)d_in[8];
  const float* fcW  = (const float*)d_in[9];
  const float* fcb  = (const float*)d_in[10];
  const float* Q    = (const float*)d_in[11];
  const float* delta= (const float*)d_in[12];
  const float* f1W  = (const float*)d_in[13];
  const float* f1b  = (const float*)d_in[14];
  const float* f2W  = (const float*)d_in[15];
  const float* f2b  = (const float*)d_in[16];
  // d_in[17] = U0 (unused by reference)
  const float* R0   = (const float*)d_in[18];
  const float* C1   = (const float*)d_in[19];
  const float* R1   = (const float*)d_in[20];
  const float* binom= (const float*)d_in[21];

  float* out = (float*)d_out;
  float* ws  = (float*)d_ws;

  hipLaunchKernelGGL(rnn_chain_kernel, dim3(64), dim3(1024), 0, stream, x,
                     Wih0, Whh0, bih0, bhh0, Wih1, Whh1, bih1, bhh1, fcW, fcb,
                     f1W, f1b, f2W, f2b, C1, R1, binom, out, ws);
  hipLaunchKernelGGL(assemble_kernel, dim3(64), dim3(64), 0, stream, x, Q,
                     delta, R0, ws, out);
}

// Round 9
// 1812.142 us; speedup vs baseline: 1.5245x; 1.5245x over previous
//
#include <hip/hip_runtime.h>

// Fsmm_rnn: 2-layer tanh RNN (B=64,T=2048,D=4,H=256) + closed-form last-step
// grad + fractional-memory Up at t=T-1 + (64,64) broadcast assemblies.
//
// v7: INT8 weights + v_dot4_i32_i8. Allocator law (v1..v6): VGPR budget is
// set by flat-workgroup-size alone (512thr -> 128) and ALL occupancy
// attributes are inert. f16 weights can never fit (192 regs @512thr).
// Int8 half-rows: 3 x 32 uints = 96 regs + ~25 working <= 128 -> no spill.
// Per-row weight scales (exact int32 accumulation via sdot4, f32 combine);
// h quantized to fixed 1/127 scale (tanh-bounded) stored as int8 in LDS.
// Structure otherwise = v2/v3: 512 thr, thread (j,half), fused step,
// 2 barriers/step.

#define TT 2048
#define HH 256
#define WIN 64

typedef uint uvec32 __attribute__((ext_vector_type(32)));

#if __has_builtin(__builtin_amdgcn_sdot4)
__device__ __forceinline__ int sdot4(uint a, uint b, int c) {
  return __builtin_amdgcn_sdot4((int)a, (int)b, c, false);
}
#else
__device__ __forceinline__ int sdot4(uint a, uint b, int c) {
#pragma unroll
  for (int k = 0; k < 4; ++k) {
    int av = (int)(a << (24 - 8 * k)) >> 24;
    int bv = (int)(b << (24 - 8 * k)) >> 24;
    c += av * bv;
  }
  return c;
}
#endif

__device__ __forceinline__ float tanh_fast(float x) {
  float xc = fminf(fmaxf(x, -15.f), 15.f);
  float e = __expf(2.f * xc);
  return (e - 1.f) * __builtin_amdgcn_rcpf(e + 1.f);
}

// 512-thread (8-wave) block sum, broadcast to all threads.
__device__ __forceinline__ float block_sum8(float v, float* red, int tid) {
#pragma unroll
  for (int off = 32; off >= 1; off >>= 1) v += __shfl_down(v, off, 64);
  __syncthreads();
  if ((tid & 63) == 0) red[tid >> 6] = v;
  __syncthreads();
  float s = 0.f;
#pragma unroll
  for (int w = 0; w < 8; ++w) s += red[w];
  return s;
}

// abs-max of a 128-col half-row (f32 global).
__device__ __forceinline__ float max_half(const float* __restrict__ base) {
  const float4* g = (const float4*)base;
  float m = 0.f;
#pragma unroll
  for (int i = 0; i < 32; ++i) {
    float4 a = g[i];
    m = fmaxf(m, fmaxf(fmaxf(fabsf(a.x), fabsf(a.y)),
                       fmaxf(fabsf(a.z), fabsf(a.w))));
  }
  return m;
}

// quantize a 128-col half-row to packed int8 (32 uints, SSA vector).
__device__ __forceinline__ uvec32 quant_half(const float* __restrict__ base,
                                             float inv) {
  uvec32 w;
  const float4* g = (const float4*)base;
#pragma unroll
  for (int i = 0; i < 32; ++i) {
    float4 a = g[i];
    int b0 = (int)rintf(a.x * inv), b1 = (int)rintf(a.y * inv);
    int b2 = (int)rintf(a.z * inv), b3 = (int)rintf(a.w * inv);
    w[i] = (uint)(b0 & 0xFF) | ((uint)(b1 & 0xFF) << 8) |
           ((uint)(b2 & 0xFF) << 16) | ((uint)(b3 & 0xFF) << 24);
  }
  return w;
}

// 128-col int8 half-row dot vs broadcast qh (8 uint4 uniform LDS reads).
#define IDOTHALF(WV, HP, ACC)                                              \
  {                                                                        \
    _Pragma("unroll") for (int _i = 0; _i < 8; ++_i) {                     \
      uint4 _u = (HP)[_i];                                                 \
      ACC = sdot4(WV[4 * _i + 0], _u.x, ACC);                              \
      ACC = sdot4(WV[4 * _i + 1], _u.y, ACC);                              \
      ACC = sdot4(WV[4 * _i + 2], _u.z, ACC);                              \
      ACC = sdot4(WV[4 * _i + 3], _u.w, ACC);                              \
    }                                                                      \
  }

__global__ __launch_bounds__(512) void rnn_chain_kernel(
    const float* __restrict__ x, const float* __restrict__ Wih0,
    const float* __restrict__ Whh0, const float* __restrict__ bih0,
    const float* __restrict__ bhh0, const float* __restrict__ Wih1,
    const float* __restrict__ Whh1, const float* __restrict__ bih1,
    const float* __restrict__ bhh1, const float* __restrict__ fcW,
    const float* __restrict__ fcb, const float* __restrict__ f1W,
    const float* __restrict__ f1b, const float* __restrict__ f2W,
    const float* __restrict__ f2b, const float* __restrict__ C1,
    const float* __restrict__ R1, const float* __restrict__ binom,
    float* __restrict__ out_soc,  // d_out[0..64)
    float* __restrict__ ws)       // [0..64) d_soc, [64..128) f_soc, [128..192) Up_last
{
  const int b = blockIdx.x;
  const int tid = threadIdx.x;
  const int j = tid & 255;    // row
  const int half = tid >> 8;  // 0: cols 0..127, 1: cols 128..255

  __shared__ __align__(16) float xs[TT * 4];  // 32 KB: whole x[b]
  __shared__ __align__(16) uint qh0L[HH / 4]; // h0 as int8 (256 B)
  __shared__ __align__(16) uint qh1L[HH / 4]; // h1 as int8
  __shared__ float fpZ0[2 * HH];              // z0 partials (scaled f32)
  __shared__ float fpZ1[2 * HH];              // z1 partials
  __shared__ float sMax[3][2][HH];            // row-max combine (6 KB)
  __shared__ float red[8];
  __shared__ float uL[HH];

  // ---- preload x[b] into LDS (coalesced float4) ----
  const float4* xg = (const float4*)(x + (size_t)b * TT * 4);
  float4* xl = (float4*)xs;
  for (int i = tid; i < TT; i += 512) xl[i] = xg[i];

  // ---- pass 1: per-row abs-max of each matrix half-row ----
  const size_t roff = (size_t)j * HH + half * 128;
  sMax[0][half][j] = max_half(Whh0 + roff);
  sMax[1][half][j] = max_half(Wih1 + roff);
  sMax[2][half][j] = max_half(Whh1 + roff);
  __syncthreads();
  const float m0 = fmaxf(sMax[0][0][j], sMax[0][1][j]);
  const float m1 = fmaxf(sMax[1][0][j], sMax[1][1][j]);
  const float m2 = fmaxf(sMax[2][0][j], sMax[2][1][j]);
  // z factors: w ~ qw*(rowmax/127), h ~ qh/127  =>  F = rowmax/16129
  const float F0 = m0 * (1.f / 16129.f);
  const float F1i = m1 * (1.f / 16129.f);
  const float F1h = m2 * (1.f / 16129.f);
  // ---- pass 2: quantize half-rows into SSA uvec32 (96 VGPRs) ----
  const uvec32 w0 = quant_half(Whh0 + roff, m0 > 0.f ? 127.f / m0 : 0.f);
  const uvec32 w1i = quant_half(Wih1 + roff, m1 > 0.f ? 127.f / m1 : 0.f);
  const uvec32 w1h = quant_half(Whh1 + roff, m2 > 0.f ? 127.f / m2 : 0.f);

  const float4 wx = ((const float4*)Wih0)[j];  // row j of Wih0 (D=4)
  const float mybias = half ? (bih1[j] + bhh1[j]) : (bih0[j] + bhh0[j]);

  __syncthreads();  // xs ready; sMax reads done

  // ---- prologue: h0[0] = tanh(Wih0 x0 + b0), h1[-1] = 0 ----
  if (half == 0) {
    float4 x0v = xl[0];
    float h00 = tanh_fast(wx.x * x0v.x + wx.y * x0v.y + wx.z * x0v.z +
                          wx.w * x0v.w + mybias);
    ((char*)qh0L)[j] = (char)(int)rintf(h00 * 127.f);
  }
  if (tid < HH / 4) qh1L[tid] = 0u;
  __syncthreads();

  const uint4* h0p = (const uint4*)qh0L + half * 8;  // my half of qh0
  const uint4* h1p = (const uint4*)qh1L + half * 8;

  float myhT = 0.f;  // half0: f32 h0[T-1]; half1: f32 h1[T-1]

  // ---- fused scan: iteration t computes h1[t] and h0[t+1]; t = 0..T-2 ----
  for (int t = 0; t < TT - 1; ++t) {
    int C = 0, E = 0, A = 0;
    IDOTHALF(w1h, h1p, C);
    // shared pass over qh0: e (Wih1) and a (Whh0)
#pragma unroll
    for (int i = 0; i < 8; ++i) {
      uint4 u = h0p[i];
      E = sdot4(w1i[4 * i + 0], u.x, E);
      A = sdot4(w0[4 * i + 0], u.x, A);
      E = sdot4(w1i[4 * i + 1], u.y, E);
      A = sdot4(w0[4 * i + 1], u.y, A);
      E = sdot4(w1i[4 * i + 2], u.z, E);
      A = sdot4(w0[4 * i + 2], u.z, A);
      E = sdot4(w1i[4 * i + 3], u.w, E);
      A = sdot4(w0[4 * i + 3], u.w, A);
    }
    fpZ1[half * HH + j] = F1i * (float)E + F1h * (float)C;
    fpZ0[half * HH + j] = F0 * (float)A;
    __syncthreads();
    if (half == 1) {
      float z1 = fpZ1[j] + fpZ1[HH + j] + mybias;
      myhT = tanh_fast(z1);
      ((char*)qh1L)[j] = (char)(int)rintf(myhT * 127.f);
    } else {
      float4 xt = xl[t + 1];
      float z0 = fpZ0[j] + fpZ0[HH + j] + wx.x * xt.x + wx.y * xt.y +
                 wx.z * xt.z + wx.w * xt.w + mybias;
      myhT = tanh_fast(z0);
      ((char*)qh0L)[j] = (char)(int)rintf(myhT * 127.f);
    }
    __syncthreads();
  }

  // ---- final step: h1[T-1] only ----
  {
    int C = 0, E = 0;
    IDOTHALF(w1h, h1p, C);
    IDOTHALF(w1i, h0p, E);
    fpZ1[half * HH + j] = F1i * (float)E + F1h * (float)C;
    __syncthreads();
    if (half == 1) {
      float z1 = fpZ1[j] + fpZ1[HH + j] + mybias;
      myhT = tanh_fast(z1);
    }
    __syncthreads();
  }
  // Now: half0 threads hold f32 h0T = h0[T-1]; half1 threads hold f32 h1T.

  // ---- epilogue ----
  const float fw = fcW[j];

  float socb = block_sum8(half == 1 ? fw * myhT : 0.f, red, tid) + fcb[0];
  if (tid == 0) out_soc[b] = socb;

  float fsv = (half == 1) ? f2W[j] * (socb * f1W[j] + f1b[j]) : 0.f;
  float fsb = block_sum8(fsv, red, tid) + f2b[0];
  if (tid == 0) ws[64 + b] = fsb;

  // d_soc: u[k] = fcW[k](1-h1T[k]^2); g[h] = sum_k u[k] Wih1[k,h];
  //        dsoc = sum_h g[h] (1-h0T[h]^2) Wih0[h,3]   (exact f32 weights)
  if (half == 1) uL[j] = fw * (1.f - myhT * myhT);
  __syncthreads();
  float g = 0.f;
  {
    const int k0 = half * 128;
#pragma unroll 8
    for (int k = 0; k < 128; ++k)
      g += uL[k0 + k] * Wih1[(size_t)(k0 + k) * HH + j];  // coalesced over j
  }
  if (half == 1) fpZ0[j] = g;
  __syncthreads();
  float dsv = 0.f;
  if (half == 0) dsv = (g + fpZ0[j]) * (1.f - myhT * myhT) * wx.w;
  float dsoc = block_sum8(dsv, red, tid);
  if (tid == 0) ws[b] = dsoc;

  // Up[:, -1]: Ts = sqrt((time[T-1]-time[T-64])/63); hist = sum binom[k+1]*v[T-64+k]
  float histv = 0.f;
  if (tid < WIN) histv = binom[tid + 1] * xs[(TT - WIN + tid) * 4 + 0];
  float hist = block_sum8(histv, red, tid);
  if (tid == 0) {
    float tl = xs[(TT - 1) * 4 + 3], t0v = xs[(TT - WIN) * 4 + 3];
    float tdiff = (tl - t0v) * (1.0f / (float)(WIN - 1));
    float Ts = sqrtf(tdiff);
    float vlast = xs[(TT - 1) * 4 + 0], Ilast = xs[(TT - 1) * 4 + 1];
    float r1 = R1[0], c1v = C1[0];
    float up = -Ts / (r1 * c1v) * vlast + Ts / c1v * Ilast - hist;
    ws[128 + b] = up;
  }
}

__global__ void assemble_kernel(const float* __restrict__ x,
                                const float* __restrict__ Q,
                                const float* __restrict__ delta,
                                const float* __restrict__ R0,
                                const float* __restrict__ ws,
                                float* __restrict__ out) {
  const int i = blockIdx.x;    // row (batch)
  const int jj = threadIdx.x;  // col 0..63
  const float dq = delta[0] / Q[0];
  const size_t base = ((size_t)i * TT + (TT - 1)) * 4;
  const float xv0 = x[base + 0];
  const float xv1 = x[base + 1];
  const float fs = ws[64 + i];
  // loss1[i,j] = delta/Q * x[i,-1,1] + d_soc[j]
  out[64 + i * 64 + jj] = dq * xv1 + ws[jj];
  // loss2[i,j] = f_soc[i] - x[i,-1,0] - R0*x[i,-1,1] - Up_last[j]
  out[64 + 4096 + i * 64 + jj] = fs - xv0 - R0[0] * xv1 - ws[128 + jj];
}

extern "C" void kernel_launch(void* const* d_in, const int* in_sizes, int n_in,
                              void* d_out, int out_size, void* d_ws,
                              size_t ws_size, hipStream_t stream) {
  const float* x    = (const float*)d_in[0];
  const float* Wih0 = (const float*)d_in[1];
  const float* Whh0 = (const float*)d_in[2];
  const float* bih0 = (const float*)d_in[3];
  const float* bhh0 = (const float*)d_in[4];
  const float* Wih1 = (const float*)d_in[5];
  const float* Whh1 = (const float*)d_in[6];
  const float* bih1 = (const float*)d_in[7];
  const float* bhh1 = (const float*)d_in[8];
  const float* fcW  = (const float*)d_in[9];
  const float* fcb  = (const float*)d_in[10];
  const float* Q    = (const float*)d_in[11];
  const float* delta= (const float*)d_in[12];
  const float* f1W  = (const float*)d_in[13];
  const float* f1b  = (const float*)d_in[14];
  const float* f2W  = (const float*)d_in[15];
  const float* f2b  = (const float*)d_in[16];
  // d_in[17] = U0 (unused by reference)
  const float* R0   = (const float*)d_in[18];
  const float* C1   = (const float*)d_in[19];
  const float* R1   = (const float*)d_in[20];
  const float* binom= (const float*)d_in[21];

  float* out = (float*)d_out;
  float* ws  = (float*)d_ws;

  hipLaunchKernelGGL(rnn_chain_kernel, dim3(64), dim3(512), 0, stream, x,
                     Wih0, Whh0, bih0, bhh0, Wih1, Whh1, bih1, bhh1, fcW, fcb,
                     f1W, f1b, f2W, f2b, C1, R1, binom, out, ws);
  hipLaunchKernelGGL(assemble_kernel, dim3(64), dim3(64), 0, stream, x, Q,
                     delta, R0, ws, out);
}

// Round 10
// 1716.427 us; speedup vs baseline: 1.6095x; 1.0558x over previous
//
#include <hip/hip_runtime.h>

// Fsmm_rnn: 2-layer tanh RNN (B=64,T=2048,D=4,H=256) + closed-form last-step
// grad + fractional-memory Up at t=T-1 + (64,64) broadcast assemblies.
//
// v8: 1024 thr/block (16 waves, 4/SIMD; allocator law: budget 64 VGPR).
// Int8 QUARTER-rows: 3 x 16 uints = 48 weight regs (SSA vectors) + ~15
// working <= 64 -> fits by construction. Demand cuts vs v7:
//  - raw int32 partial planes (exact sums; F scale factors only on the
//    combiner waves q0/q1)
//  - xdot[j][t] = Wih0[j]·x[t]+bias0 precomputed into d_ws (prologue pass
//    via LDS-staged x); scan reads it with a 2-step-ahead prefetch
//  - wave-uniform LDS bases -> SGPR
// 4 waves/SIMD doubles latency hiding; per-thread LDS reads halve (8 b128).
// v7 measured 0.85us/step (2 waves/SIMD, 16 b128/thr); floor here ~0.3.

#define TT 2048
#define HH 256
#define WIN 64

typedef uint uvec16 __attribute__((ext_vector_type(16)));

#if __has_builtin(__builtin_amdgcn_sdot4)
__device__ __forceinline__ int sdot4(uint a, uint b, int c) {
  return __builtin_amdgcn_sdot4((int)a, (int)b, c, false);
}
#else
__device__ __forceinline__ int sdot4(uint a, uint b, int c) {
#pragma unroll
  for (int k = 0; k < 4; ++k) {
    int av = (int)(a << (24 - 8 * k)) >> 24;
    int bv = (int)(b << (24 - 8 * k)) >> 24;
    c += av * bv;
  }
  return c;
}
#endif

__device__ __forceinline__ float tanh_fast(float x) {
  float xc = fminf(fmaxf(x, -15.f), 15.f);
  float e = __expf(2.f * xc);
  return (e - 1.f) * __builtin_amdgcn_rcpf(e + 1.f);
}

// 1024-thread (16-wave) block sum, broadcast to all threads.
__device__ __forceinline__ float block_sum16(float v, float* red, int tid) {
#pragma unroll
  for (int off = 32; off >= 1; off >>= 1) v += __shfl_down(v, off, 64);
  __syncthreads();
  if ((tid & 63) == 0) red[tid >> 6] = v;
  __syncthreads();
  float s = 0.f;
#pragma unroll
  for (int w = 0; w < 16; ++w) s += red[w];
  return s;
}

// abs-max of a 64-col quarter row (f32 global).
__device__ __forceinline__ float max_quarter(const float* __restrict__ base) {
  const float4* g = (const float4*)base;
  float m = 0.f;
#pragma unroll
  for (int i = 0; i < 16; ++i) {
    float4 a = g[i];
    m = fmaxf(m, fmaxf(fmaxf(fabsf(a.x), fabsf(a.y)),
                       fmaxf(fabsf(a.z), fabsf(a.w))));
  }
  return m;
}

// quantize a 64-col quarter row to packed int8 (16 uints, SSA vector).
__device__ __forceinline__ uvec16 quant_quarter(const float* __restrict__ base,
                                                float inv) {
  uvec16 w;
  const float4* g = (const float4*)base;
#pragma unroll
  for (int i = 0; i < 16; ++i) {
    float4 a = g[i];
    int b0 = (int)rintf(a.x * inv), b1 = (int)rintf(a.y * inv);
    int b2 = (int)rintf(a.z * inv), b3 = (int)rintf(a.w * inv);
    w[i] = (uint)(b0 & 0xFF) | ((uint)(b1 & 0xFF) << 8) |
           ((uint)(b2 & 0xFF) << 16) | ((uint)(b3 & 0xFF) << 24);
  }
  return w;
}

__global__ __launch_bounds__(1024) void rnn_chain_kernel(
    const float* __restrict__ x, const float* __restrict__ Wih0,
    const float* __restrict__ Whh0, const float* __restrict__ bih0,
    const float* __restrict__ bhh0, const float* __restrict__ Wih1,
    const float* __restrict__ Whh1, const float* __restrict__ bih1,
    const float* __restrict__ bhh1, const float* __restrict__ fcW,
    const float* __restrict__ fcb, const float* __restrict__ f1W,
    const float* __restrict__ f1b, const float* __restrict__ f2W,
    const float* __restrict__ f2b, const float* __restrict__ C1,
    const float* __restrict__ R1, const float* __restrict__ binom,
    float* __restrict__ out_soc,  // d_out[0..64)
    float* __restrict__ ws)       // small outputs [0..192); xdot at +1024
{
  const int b = blockIdx.x;
  const int tid = threadIdx.x;
  const int j = tid & 255;  // row
  const int q = tid >> 8;   // quarter: cols [64q, 64q+64)

  __shared__ __align__(16) float xs[TT * 4];   // 32 KB: whole x[b]
  __shared__ __align__(16) uint qh0L[HH / 4];  // h0 int8 (256 B)
  __shared__ __align__(16) uint qh1L[HH / 4];  // h1 int8
  __shared__ int pA_[4 * HH];                  // Whh0 partials (int, exact)
  __shared__ int pE_[4 * HH];                  // Wih1 partials
  __shared__ int pC_[4 * HH];                  // Whh1 partials
  __shared__ float sMax[3][4][HH];             // row-max combine (12 KB)
  __shared__ float pF[4 * HH];                 // f32 plane (d_soc combine)
  __shared__ float red[16];
  __shared__ float uL[HH];

  // ---- 1. stage x[b] in LDS (coalesced float4) ----
  const float4* xg = (const float4*)(x + (size_t)b * TT * 4);
  float4* xl = (float4*)xs;
  for (int i = tid; i < TT; i += 1024) xl[i] = xg[i];
  __syncthreads();

  // ---- 2. xdot[t][j] = Wih0[j]·x[t] + bias0[j] into d_ws (my t-range) ----
  float* xdb = ws + 1024 + (size_t)b * TT * HH;
  float xd0 = 0.f, xd1 = 0.f;  // q0 keeps t=0,1 values in regs
  {
    const float4 wx = ((const float4*)Wih0)[j];
    const float b0 = bih0[j] + bhh0[j];
    const int t0 = q * (TT / 4);
#pragma unroll 4
    for (int t = t0; t < t0 + TT / 4; ++t) {
      float4 xv = xl[t];  // uniform broadcast
      float d = wx.x * xv.x + wx.y * xv.y + wx.z * xv.z + wx.w * xv.w + b0;
      xdb[(size_t)t * HH + j] = d;
      if (t == 0) xd0 = d;
      if (t == 1) xd1 = d;
    }
  }

  // ---- 3. per-row abs-max (quarters), combine ----
  const size_t roff = (size_t)j * HH + q * 64;
  sMax[0][q][j] = max_quarter(Whh0 + roff);
  sMax[1][q][j] = max_quarter(Wih1 + roff);
  sMax[2][q][j] = max_quarter(Whh1 + roff);
  __syncthreads();
  const float m0 = fmaxf(fmaxf(sMax[0][0][j], sMax[0][1][j]),
                         fmaxf(sMax[0][2][j], sMax[0][3][j]));
  const float m1 = fmaxf(fmaxf(sMax[1][0][j], sMax[1][1][j]),
                         fmaxf(sMax[1][2][j], sMax[1][3][j]));
  const float m2 = fmaxf(fmaxf(sMax[2][0][j], sMax[2][1][j]),
                         fmaxf(sMax[2][2][j], sMax[2][3][j]));

  // ---- 4. quantize quarter-rows into SSA vectors (48 VGPRs) ----
  const uvec16 w0 = quant_quarter(Whh0 + roff, m0 > 0.f ? 127.f / m0 : 0.f);
  const uvec16 w1i = quant_quarter(Wih1 + roff, m1 > 0.f ? 127.f / m1 : 0.f);
  const uvec16 w1h = quant_quarter(Whh1 + roff, m2 > 0.f ? 127.f / m2 : 0.f);

  // scale factors only where consumed (wave-uniform roles)
  const float F0 = (q == 0) ? m0 * (1.f / 16129.f) : 0.f;
  const float F1i = (q == 1) ? m1 * (1.f / 16129.f) : 0.f;
  const float F1h = (q == 1) ? m2 * (1.f / 16129.f) : 0.f;
  const float bias1 = (q == 1) ? (bih1[j] + bhh1[j]) : 0.f;

  // ---- 5. init: h0[0] = tanh(xdot[0]); h1[-1] = 0 ----
  if (q == 0) {
    float h00 = tanh_fast(xd0);
    ((char*)qh0L)[j] = (char)(int)rintf(h00 * 127.f);
  }
  if (tid < HH / 4) qh1L[tid] = 0u;
  float xdn = xd1;  // q0: xdot[t+1] for t=0
  __syncthreads();

  const uint4* h0p = (const uint4*)qh0L + q * 4;  // my 64-B quarter of qh0
  const uint4* h1p = (const uint4*)qh1L + q * 4;

  float myhT = 0.f;  // q0: f32 h0[T-1]; q1: f32 h1[T-1]

  // ---- fused scan: iteration t computes h1[t] and h0[t+1]; t = 0..T-2 ----
  for (int t = 0; t < TT - 1; ++t) {
    // prefetch xdot[t+2] (2 steps ahead covers HBM latency)
    float xnn = 0.f;
    if (q == 0) {
      int idx = (t + 2 < TT) ? t + 2 : TT - 1;
      xnn = xdb[(size_t)idx * HH + j];
    }
    // C = Whh1 quarter . h1[t-1]
    int C = 0;
#pragma unroll
    for (int i = 0; i < 4; ++i) {
      uint4 u = h1p[i];
      C = sdot4(w1h[4 * i + 0], u.x, C);
      C = sdot4(w1h[4 * i + 1], u.y, C);
      C = sdot4(w1h[4 * i + 2], u.z, C);
      C = sdot4(w1h[4 * i + 3], u.w, C);
    }
    // shared pass over h0[t]: E (Wih1) and A (Whh0)
    int E = 0, A = 0;
#pragma unroll
    for (int i = 0; i < 4; ++i) {
      uint4 u = h0p[i];
      E = sdot4(w1i[4 * i + 0], u.x, E);
      A = sdot4(w0[4 * i + 0], u.x, A);
      E = sdot4(w1i[4 * i + 1], u.y, E);
      A = sdot4(w0[4 * i + 1], u.y, A);
      E = sdot4(w1i[4 * i + 2], u.z, E);
      A = sdot4(w0[4 * i + 2], u.z, A);
      E = sdot4(w1i[4 * i + 3], u.w, E);
      A = sdot4(w0[4 * i + 3], u.w, A);
    }
    pA_[q * HH + j] = A;
    pE_[q * HH + j] = E;
    pC_[q * HH + j] = C;
    __syncthreads();
    if (q == 0) {
      float z0 = F0 * (float)(pA_[j] + pA_[HH + j] + pA_[2 * HH + j] +
                              pA_[3 * HH + j]) +
                 xdn;
      myhT = tanh_fast(z0);
      ((char*)qh0L)[j] = (char)(int)rintf(myhT * 127.f);
    } else if (q == 1) {
      float z1 = F1i * (float)(pE_[j] + pE_[HH + j] + pE_[2 * HH + j] +
                               pE_[3 * HH + j]) +
                 F1h * (float)(pC_[j] + pC_[HH + j] + pC_[2 * HH + j] +
                               pC_[3 * HH + j]) +
                 bias1;
      myhT = tanh_fast(z1);
      ((char*)qh1L)[j] = (char)(int)rintf(myhT * 127.f);
    }
    xdn = xnn;
    __syncthreads();
  }

  // ---- final step: h1[T-1] only ----
  {
    int C = 0, E = 0;
#pragma unroll
    for (int i = 0; i < 4; ++i) {
      uint4 u = h1p[i];
      C = sdot4(w1h[4 * i + 0], u.x, C);
      C = sdot4(w1h[4 * i + 1], u.y, C);
      C = sdot4(w1h[4 * i + 2], u.z, C);
      C = sdot4(w1h[4 * i + 3], u.w, C);
    }
#pragma unroll
    for (int i = 0; i < 4; ++i) {
      uint4 u = h0p[i];
      E = sdot4(w1i[4 * i + 0], u.x, E);
      E = sdot4(w1i[4 * i + 1], u.y, E);
      E = sdot4(w1i[4 * i + 2], u.z, E);
      E = sdot4(w1i[4 * i + 3], u.w, E);
    }
    pE_[q * HH + j] = E;
    pC_[q * HH + j] = C;
    __syncthreads();
    if (q == 1) {
      float z1 = F1i * (float)(pE_[j] + pE_[HH + j] + pE_[2 * HH + j] +
                               pE_[3 * HH + j]) +
                 F1h * (float)(pC_[j] + pC_[HH + j] + pC_[2 * HH + j] +
                               pC_[3 * HH + j]) +
                 bias1;
      myhT = tanh_fast(z1);
    }
    __syncthreads();
  }
  // q0 threads hold f32 h0T = h0[T-1]; q1 threads hold f32 h1T = h1[T-1].

  // ---- epilogue ----
  const float fw = fcW[j];

  float socb = block_sum16(q == 1 ? fw * myhT : 0.f, red, tid) + fcb[0];
  if (tid == 0) out_soc[b] = socb;

  float fsv = (q == 1) ? f2W[j] * (socb * f1W[j] + f1b[j]) : 0.f;
  float fsb = block_sum16(fsv, red, tid) + f2b[0];
  if (tid == 0) ws[64 + b] = fsb;

  // d_soc: u[k] = fcW[k](1-h1T[k]^2); g[h] = sum_k u[k] Wih1[k,h];
  //        dsoc = sum_h g[h] (1-h0T[h]^2) Wih0[h,3]   (exact f32 weights)
  if (q == 1) uL[j] = fw * (1.f - myhT * myhT);
  __syncthreads();
  {
    float g = 0.f;
    const int k0 = q * 64;
#pragma unroll 8
    for (int k = 0; k < 64; ++k)
      g += uL[k0 + k] * Wih1[(size_t)(k0 + k) * HH + j];  // coalesced over j
    pF[q * HH + j] = g;
  }
  __syncthreads();
  float dsv = 0.f;
  if (q == 0) {
    float g = pF[j] + pF[HH + j] + pF[2 * HH + j] + pF[3 * HH + j];
    float wx3 = Wih0[j * 4 + 3];
    dsv = g * (1.f - myhT * myhT) * wx3;
  }
  float dsoc = block_sum16(dsv, red, tid);
  if (tid == 0) ws[b] = dsoc;

  // Up[:, -1]
  float histv = 0.f;
  if (tid < WIN) histv = binom[tid + 1] * xs[(TT - WIN + tid) * 4 + 0];
  float hist = block_sum16(histv, red, tid);
  if (tid == 0) {
    float tl = xs[(TT - 1) * 4 + 3], t0v = xs[(TT - WIN) * 4 + 3];
    float tdiff = (tl - t0v) * (1.0f / (float)(WIN - 1));
    float Ts = sqrtf(tdiff);
    float vlast = xs[(TT - 1) * 4 + 0], Ilast = xs[(TT - 1) * 4 + 1];
    float r1 = R1[0], c1v = C1[0];
    float up = -Ts / (r1 * c1v) * vlast + Ts / c1v * Ilast - hist;
    ws[128 + b] = up;
  }
}

__global__ void assemble_kernel(const float* __restrict__ x,
                                const float* __restrict__ Q,
                                const float* __restrict__ delta,
                                const float* __restrict__ R0,
                                const float* __restrict__ ws,
                                float* __restrict__ out) {
  const int i = blockIdx.x;    // row (batch)
  const int jj = threadIdx.x;  // col 0..63
  const float dq = delta[0] / Q[0];
  const size_t base = ((size_t)i * TT + (TT - 1)) * 4;
  const float xv0 = x[base + 0];
  const float xv1 = x[base + 1];
  const float fs = ws[64 + i];
  // loss1[i,j] = delta/Q * x[i,-1,1] + d_soc[j]
  out[64 + i * 64 + jj] = dq * xv1 + ws[jj];
  // loss2[i,j] = f_soc[i] - x[i,-1,0] - R0*x[i,-1,1] - Up_last[j]
  out[64 + 4096 + i * 64 + jj] = fs - xv0 - R0[0] * xv1 - ws[128 + jj];
}

extern "C" void kernel_launch(void* const* d_in, const int* in_sizes, int n_in,
                              void* d_out, int out_size, void* d_ws,
                              size_t ws_size, hipStream_t stream) {
  const float* x    = (const float*)d_in[0];
  const float* Wih0 = (const float*)d_in[1];
  const float* Whh0 = (const float*)d_in[2];
  const float* bih0 = (const float*)d_in[3];
  const float* bhh0 = (const float*)d_in[4];
  const float* Wih1 = (const float*)d_in[5];
  const float* Whh1 = (const float*)d_in[6];
  const float* bih1 = (const float*)d_in[7];
  const float* bhh1 = (const float*)d_in[8];
  const float* fcW  = (const float*)d_in[9];
  const float* fcb  = (const float*)d_in[10];
  const float* Q    = (const float*)d_in[11];
  const float* delta= (const float*)d_in[12];
  const float* f1W  = (const float*)d_in[13];
  const float* f1b  = (const float*)d_in[14];
  const float* f2W  = (const float*)d_in[15];
  const float* f2b  = (const float*)d_in[16];
  // d_in[17] = U0 (unused by reference)
  const float* R0   = (const float*)d_in[18];
  const float* C1   = (const float*)d_in[19];
  const float* R1   = (const float*)d_in[20];
  const float* binom= (const float*)d_in[21];

  float* out = (float*)d_out;
  float* ws  = (float*)d_ws;

  hipLaunchKernelGGL(rnn_chain_kernel, dim3(64), dim3(1024), 0, stream, x,
                     Wih0, Whh0, bih0, bhh0, Wih1, Whh1, bih1, bhh1, fcW, fcb,
                     f1W, f1b, f2W, f2b, C1, R1, binom, out, ws);
  hipLaunchKernelGGL(assemble_kernel, dim3(64), dim3(64), 0, stream, x, Q,
                     delta, R0, ws, out);
}

// Round 11
// 1617.104 us; speedup vs baseline: 1.7083x; 1.0614x over previous
//
#include <hip/hip_runtime.h>

// Fsmm_rnn: 2-layer tanh RNN (B=64,T=2048,D=4,H=256) + closed-form last-step
// grad + fractional-memory Up at t=T-1 + (64,64) broadcast assemblies.
//
// v9: same-wave half-split + shfl combine + 1 barrier/step.
// v8 post-mortem: step cost (~1970cy) was the serial partial-plane LDS
// round-trip (write->barrier->4 plane reads->tanh->h write) + 2 barriers x16
// waves, NOT issue (halving per-thread work changed nothing); xdot precompute
// added 107MB F + 202MB W of HBM. Fix: lane l<32 holds cols 0..127 of row
// j=32w+(l&31), lane l+32 holds cols 128..255 -> cross-half combine is
// __shfl_xor(acc,32) (exact int32, ~10cy, no LDS, no barrier); h int8
// double-buffered (2x256B) -> ONE barrier/step; branchless z-select + single
// tanh + per-lane-addressed ds_write_b8; xdot recomputed inline (4 FMA off a
// uniform broadcast). 512 thr -> 128-VGPR budget; demand 96 weight uints +
// ~23 working = ~119 (v7 proved the envelope).

#define TT 2048
#define HH 256
#define WIN 64

typedef uint uvec32 __attribute__((ext_vector_type(32)));

#if __has_builtin(__builtin_amdgcn_sdot4)
__device__ __forceinline__ int sdot4(uint a, uint b, int c) {
  return __builtin_amdgcn_sdot4((int)a, (int)b, c, false);
}
#else
__device__ __forceinline__ int sdot4(uint a, uint b, int c) {
#pragma unroll
  for (int k = 0; k < 4; ++k) {
    int av = (int)(a << (24 - 8 * k)) >> 24;
    int bv = (int)(b << (24 - 8 * k)) >> 24;
    c += av * bv;
  }
  return c;
}
#endif

__device__ __forceinline__ float tanh_fast(float x) {
  float xc = fminf(fmaxf(x, -15.f), 15.f);
  float e = __expf(2.f * xc);
  return (e - 1.f) * __builtin_amdgcn_rcpf(e + 1.f);
}

// 512-thread (8-wave) block sum, broadcast to all threads.
__device__ __forceinline__ float block_sum8(float v, float* red, int tid) {
#pragma unroll
  for (int off = 32; off >= 1; off >>= 1) v += __shfl_down(v, off, 64);
  __syncthreads();
  if ((tid & 63) == 0) red[tid >> 6] = v;
  __syncthreads();
  float s = 0.f;
#pragma unroll
  for (int w = 0; w < 8; ++w) s += red[w];
  return s;
}

// abs-max of a 128-col half-row (f32 global).
__device__ __forceinline__ float max_half(const float* __restrict__ base) {
  const float4* g = (const float4*)base;
  float m = 0.f;
#pragma unroll
  for (int i = 0; i < 32; ++i) {
    float4 a = g[i];
    m = fmaxf(m, fmaxf(fmaxf(fabsf(a.x), fabsf(a.y)),
                       fmaxf(fabsf(a.z), fabsf(a.w))));
  }
  return m;
}

// quantize a 128-col half-row to packed int8 (32 uints, SSA vector).
__device__ __forceinline__ uvec32 quant_half(const float* __restrict__ base,
                                             float inv) {
  uvec32 w;
  const float4* g = (const float4*)base;
#pragma unroll
  for (int i = 0; i < 32; ++i) {
    float4 a = g[i];
    int b0 = (int)rintf(a.x * inv), b1 = (int)rintf(a.y * inv);
    int b2 = (int)rintf(a.z * inv), b3 = (int)rintf(a.w * inv);
    w[i] = (uint)(b0 & 0xFF) | ((uint)(b1 & 0xFF) << 8) |
           ((uint)(b2 & 0xFF) << 16) | ((uint)(b3 & 0xFF) << 24);
  }
  return w;
}

__global__ __launch_bounds__(512) void rnn_chain_kernel(
    const float* __restrict__ x, const float* __restrict__ Wih0,
    const float* __restrict__ Whh0, const float* __restrict__ bih0,
    const float* __restrict__ bhh0, const float* __restrict__ Wih1,
    const float* __restrict__ Whh1, const float* __restrict__ bih1,
    const float* __restrict__ bhh1, const float* __restrict__ fcW,
    const float* __restrict__ fcb, const float* __restrict__ f1W,
    const float* __restrict__ f1b, const float* __restrict__ f2W,
    const float* __restrict__ f2b, const float* __restrict__ C1,
    const float* __restrict__ R1, const float* __restrict__ binom,
    float* __restrict__ out_soc,  // d_out[0..64)
    float* __restrict__ ws)       // [0..64) d_soc, [64..128) f_soc, [128..192) Up_last
{
  const int b = blockIdx.x;
  const int tid = threadIdx.x;
  const int lane = tid & 63;
  const int wv = tid >> 6;          // wave 0..7
  const int half = lane >> 5;       // 0: cols 0..127, 1: cols 128..255
  const int j = (wv << 5) | (lane & 31);  // row 0..255 (each row: 2 lanes, same wave)

  __shared__ __align__(16) float xs[TT * 4];        // 32 KB: whole x[b]
  __shared__ __align__(16) uint qh0L[2][HH / 4];    // h0 int8, double-buffered
  __shared__ __align__(16) uint qh1L[2][HH / 4];    // h1 int8
  __shared__ float red[8];
  __shared__ float uL[HH];    // fcW*(1-h1T^2)
  __shared__ float s0L[HH];   // (1-h0T^2)*Wih0[:,3]
  __shared__ float pF[2 * HH];

  // ---- stage x[b] in LDS (coalesced float4) ----
  const float4* xg = (const float4*)(x + (size_t)b * TT * 4);
  float4* xl = (float4*)xs;
  for (int i = tid; i < TT; i += 512) xl[i] = xg[i];

  // ---- per-row abs-max via shfl (no LDS) ----
  const size_t roff = (size_t)j * HH + half * 128;
  float mm0 = max_half(Whh0 + roff);
  float mm1 = max_half(Wih1 + roff);
  float mm2 = max_half(Whh1 + roff);
  const float m0 = fmaxf(mm0, __shfl_xor(mm0, 32));
  const float m1 = fmaxf(mm1, __shfl_xor(mm1, 32));
  const float m2 = fmaxf(mm2, __shfl_xor(mm2, 32));

  // ---- quantize half-rows into SSA vectors (96 VGPRs) ----
  const uvec32 w0 = quant_half(Whh0 + roff, m0 > 0.f ? 127.f / m0 : 0.f);
  const uvec32 w1i = quant_half(Wih1 + roff, m1 > 0.f ? 127.f / m1 : 0.f);
  const uvec32 w1h = quant_half(Whh1 + roff, m2 > 0.f ? 127.f / m2 : 0.f);

  // z factors: w ~ qw*(rowmax/127), h ~ qh/127 => F = rowmax/16129
  const float F0 = m0 * (1.f / 16129.f);
  const float F1i = m1 * (1.f / 16129.f);
  const float F1h = m2 * (1.f / 16129.f);
  const float4 wx = ((const float4*)Wih0)[j];  // row j of Wih0 (D=4)
  const float bias0 = bih0[j] + bhh0[j];
  const float bias1 = bih1[j] + bhh1[j];

  __syncthreads();  // xs ready

  // ---- init: h0[0] = tanh(Wih0 x0 + b0) (lo lanes); h1[-1] = 0 (hi) ----
  {
    float4 x0v = xl[0];
    float xd = wx.x * x0v.x + wx.y * x0v.y + wx.z * x0v.z + wx.w * x0v.w +
               bias0;
    float h00 = tanh_fast(xd);
    char* hb = half ? (char*)&qh1L[0][0] : (char*)&qh0L[0][0];
    char v = half ? (char)0 : (char)(int)rintf(h00 * 127.f);
    hb[j] = v;
  }
  __syncthreads();

  int cur = 0;
  float myh = 0.f;  // lo lanes: h0[t+1]; hi lanes: h1[t]

  // ---- fused scan: iteration t computes h1[t] and h0[t+1]; t = 0..T-2 ----
  for (int t = 0; t < TT - 1; ++t) {
    const uint4* h0p = (const uint4*)&qh0L[cur][0] + half * 8;
    const uint4* h1p = (const uint4*)&qh1L[cur][0] + half * 8;
    int C = 0, E = 0, A = 0;
#pragma unroll
    for (int i = 0; i < 8; ++i) {
      uint4 u = h1p[i];
      C = sdot4(w1h[4 * i + 0], u.x, C);
      C = sdot4(w1h[4 * i + 1], u.y, C);
      C = sdot4(w1h[4 * i + 2], u.z, C);
      C = sdot4(w1h[4 * i + 3], u.w, C);
    }
#pragma unroll
    for (int i = 0; i < 8; ++i) {
      uint4 u = h0p[i];
      E = sdot4(w1i[4 * i + 0], u.x, E);
      A = sdot4(w0[4 * i + 0], u.x, A);
      E = sdot4(w1i[4 * i + 1], u.y, E);
      A = sdot4(w0[4 * i + 1], u.y, A);
      E = sdot4(w1i[4 * i + 2], u.z, E);
      A = sdot4(w0[4 * i + 2], u.z, A);
      E = sdot4(w1i[4 * i + 3], u.w, E);
      A = sdot4(w0[4 * i + 3], u.w, A);
    }
    // exact cross-half combine in-wave
    A += __shfl_xor(A, 32);
    E += __shfl_xor(E, 32);
    C += __shfl_xor(C, 32);
    // branchless role split: lo -> z0 (h0[t+1]), hi -> z1 (h1[t])
    float4 xt = xl[t + 1];  // uniform broadcast
    float xd = wx.x * xt.x + wx.y * xt.y + wx.z * xt.z + wx.w * xt.w + bias0;
    float z = half ? (F1i * (float)E + F1h * (float)C + bias1)
                   : (F0 * (float)A + xd);
    myh = tanh_fast(z);
    char* hb = half ? (char*)&qh1L[cur ^ 1][0] : (char*)&qh0L[cur ^ 1][0];
    hb[j] = (char)(int)rintf(myh * 127.f);
    cur ^= 1;
    __syncthreads();  // single barrier: next iter reads what was just written
  }

  // ---- final step: h1[T-1] only (lo lanes keep myh = h0[T-1]) ----
  {
    const uint4* h0p = (const uint4*)&qh0L[cur][0] + half * 8;
    const uint4* h1p = (const uint4*)&qh1L[cur][0] + half * 8;
    int C = 0, E = 0;
#pragma unroll
    for (int i = 0; i < 8; ++i) {
      uint4 u = h1p[i];
      C = sdot4(w1h[4 * i + 0], u.x, C);
      C = sdot4(w1h[4 * i + 1], u.y, C);
      C = sdot4(w1h[4 * i + 2], u.z, C);
      C = sdot4(w1h[4 * i + 3], u.w, C);
    }
#pragma unroll
    for (int i = 0; i < 8; ++i) {
      uint4 u = h0p[i];
      E = sdot4(w1i[4 * i + 0], u.x, E);
      E = sdot4(w1i[4 * i + 1], u.y, E);
      E = sdot4(w1i[4 * i + 2], u.z, E);
      E = sdot4(w1i[4 * i + 3], u.w, E);
    }
    E += __shfl_xor(E, 32);
    C += __shfl_xor(C, 32);
    if (half) myh = tanh_fast(F1i * (float)E + F1h * (float)C + bias1);
  }
  // lo lanes: myh = h0[T-1][j]; hi lanes: myh = h1[T-1][j].

  // ---- epilogue ----
  const float fw = fcW[j];

  float socb = block_sum8(half ? fw * myh : 0.f, red, tid) + fcb[0];
  if (tid == 0) out_soc[b] = socb;

  float fsv = half ? f2W[j] * (socb * f1W[j] + f1b[j]) : 0.f;
  float fsb = block_sum8(fsv, red, tid) + f2b[0];
  if (tid == 0) ws[64 + b] = fsb;

  // d_soc: u[k]=fcW[k](1-h1T[k]^2); g[h]=sum_k u[k]Wih1[k,h];
  //        dsoc=sum_h g[h](1-h0T[h]^2)Wih0[h,3]  (exact f32 weights)
  if (half) uL[j] = fw * (1.f - myh * myh);
  else      s0L[j] = (1.f - myh * myh) * wx.w;
  __syncthreads();
  {
    const int h = tid & 255;   // output column
    const int kh = tid >> 8;   // k half
    float g = 0.f;
    const int k0 = kh * 128;
#pragma unroll 8
    for (int k = 0; k < 128; ++k)
      g += uL[k0 + k] * Wih1[(size_t)(k0 + k) * HH + h];  // coalesced over h
    pF[kh * HH + h] = g;
  }
  __syncthreads();
  float dsv = 0.f;
  if (tid < HH) dsv = (pF[tid] + pF[HH + tid]) * s0L[tid];
  float dsoc = block_sum8(dsv, red, tid);
  if (tid == 0) ws[b] = dsoc;

  // Up[:, -1]
  float histv = 0.f;
  if (tid < WIN) histv = binom[tid + 1] * xs[(TT - WIN + tid) * 4 + 0];
  float hist = block_sum8(histv, red, tid);
  if (tid == 0) {
    float tl = xs[(TT - 1) * 4 + 3], t0v = xs[(TT - WIN) * 4 + 3];
    float tdiff = (tl - t0v) * (1.0f / (float)(WIN - 1));
    float Ts = sqrtf(tdiff);
    float vlast = xs[(TT - 1) * 4 + 0], Ilast = xs[(TT - 1) * 4 + 1];
    float r1 = R1[0], c1v = C1[0];
    float up = -Ts / (r1 * c1v) * vlast + Ts / c1v * Ilast - hist;
    ws[128 + b] = up;
  }
}

__global__ void assemble_kernel(const float* __restrict__ x,
                                const float* __restrict__ Q,
                                const float* __restrict__ delta,
                                const float* __restrict__ R0,
                                const float* __restrict__ ws,
                                float* __restrict__ out) {
  const int i = blockIdx.x;    // row (batch)
  const int jj = threadIdx.x;  // col 0..63
  const float dq = delta[0] / Q[0];
  const size_t base = ((size_t)i * TT + (TT - 1)) * 4;
  const float xv0 = x[base + 0];
  const float xv1 = x[base + 1];
  const float fs = ws[64 + i];
  // loss1[i,j] = delta/Q * x[i,-1,1] + d_soc[j]
  out[64 + i * 64 + jj] = dq * xv1 + ws[jj];
  // loss2[i,j] = f_soc[i] - x[i,-1,0] - R0*x[i,-1,1] - Up_last[j]
  out[64 + 4096 + i * 64 + jj] = fs - xv0 - R0[0] * xv1 - ws[128 + jj];
}

extern "C" void kernel_launch(void* const* d_in, const int* in_sizes, int n_in,
                              void* d_out, int out_size, void* d_ws,
                              size_t ws_size, hipStream_t stream) {
  const float* x    = (const float*)d_in[0];
  const float* Wih0 = (const float*)d_in[1];
  const float* Whh0 = (const float*)d_in[2];
  const float* bih0 = (const float*)d_in[3];
  const float* bhh0 = (const float*)d_in[4];
  const float* Wih1 = (const float*)d_in[5];
  const float* Whh1 = (const float*)d_in[6];
  const float* bih1 = (const float*)d_in[7];
  const float* bhh1 = (const float*)d_in[8];
  const float* fcW  = (const float*)d_in[9];
  const float* fcb  = (const float*)d_in[10];
  const float* Q    = (const float*)d_in[11];
  const float* delta= (const float*)d_in[12];
  const float* f1W  = (const float*)d_in[13];
  const float* f1b  = (const float*)d_in[14];
  const float* f2W  = (const float*)d_in[15];
  const float* f2b  = (const float*)d_in[16];
  // d_in[17] = U0 (unused by reference)
  const float* R0   = (const float*)d_in[18];
  const float* C1   = (const float*)d_in[19];
  const float* R1   = (const float*)d_in[20];
  const float* binom= (const float*)d_in[21];

  float* out = (float*)d_out;
  float* ws  = (float*)d_ws;

  hipLaunchKernelGGL(rnn_chain_kernel, dim3(64), dim3(512), 0, stream, x,
                     Wih0, Whh0, bih0, bhh0, Wih1, Whh1, bih1, bhh1, fcW, fcb,
                     f1W, f1b, f2W, f2b, C1, R1, binom, out, ws);
  hipLaunchKernelGGL(assemble_kernel, dim3(64), dim3(64), 0, stream, x, Q,
                     delta, R0, ws, out);
}